// Round 4
// baseline (340824.487 us; speedup 1.0000x reference)
//
#include <hip/hip_runtime.h>
#include <math.h>

#define HH 2048
#define DD 66
#define TT 4096
#define PRE 64
#define NWG 256
#define NTH 512
#define FSTRIDE 16   // flag padding: 16 uints = 64B per WG

// int16 row-scaled quantization: w ~= scale[row] * q, q in [-32767,32767].
// Packed layout per (4H x H) matrix: uint4 Q[(row*4+p)*64+lane] holds 8 int16 for
// columns p*512+4*lane+{0..3} (x,y) and p*512+256+4*lane+{0..3} (z,w) — matching
// h fragments hf[2p], hf[2p+1] where hf[m] = ((float4*)ldsH)[m*64+lane].
// Workspace: [Q1 33.5MB][S1 32KB][Q2a][S2a][Q2b][S2b][h1buf][h2buf][flags1][flags2]
// Equality flags (target=t+1) immune to 0xAAAAAAAA poison.

typedef unsigned int uint;

__device__ __forceinline__ float sigmoidf_(float x) { return 1.0f / (1.0f + expf(-x)); }

__device__ __forceinline__ float wred(float a) {
  #pragma unroll
  for (int s = 32; s > 0; s >>= 1) a += __shfl_xor(a, s, 64);
  return a;
}

__device__ __forceinline__ void gbar_wait(unsigned* flags, unsigned target, int tid) {
  const int idx = (tid & (NWG - 1)) * FSTRIDE;
  unsigned v = __hip_atomic_load(&flags[idx], __ATOMIC_RELAXED, __HIP_MEMORY_SCOPE_AGENT);
  while (!__syncthreads_and((int)(v == target))) {
    v = __hip_atomic_load(&flags[idx], __ATOMIC_RELAXED, __HIP_MEMORY_SCOPE_AGENT);
  }
}

// dequant-dot: one uint4 (8 int16 weights) against two float4 h-fragments.
__device__ __forceinline__ float dqdot(uint4 q, float4 ha, float4 hb, float acc) {
  acc = fmaf((float)((int)(short)(q.x & 0xffffu)), ha.x, acc);
  acc = fmaf((float)(((int)q.x) >> 16),            ha.y, acc);
  acc = fmaf((float)((int)(short)(q.y & 0xffffu)), ha.z, acc);
  acc = fmaf((float)(((int)q.y) >> 16),            ha.w, acc);
  acc = fmaf((float)((int)(short)(q.z & 0xffffu)), hb.x, acc);
  acc = fmaf((float)(((int)q.z) >> 16),            hb.y, acc);
  acc = fmaf((float)((int)(short)(q.w & 0xffffu)), hb.z, acc);
  acc = fmaf((float)(((int)q.w) >> 16),            hb.w, acc);
  return acc;
}

// One block (256 thr) per row. p = tid>>6, lane = tid&63.
__global__ void pack_q16(const float* __restrict__ src, uint4* __restrict__ q,
                         float* __restrict__ scale) {
  __shared__ float rmx[256];
  __shared__ float sinv_s;
  const int row = blockIdx.x;
  const int tid = threadIdx.x;
  const int p = tid >> 6, lane = tid & 63;
  const float* sr = src + (size_t)row * HH + p * 512 + 4 * lane;
  float4 a = *(const float4*)sr;
  float4 b = *(const float4*)(sr + 256);
  float m = fmaxf(fmaxf(fmaxf(fabsf(a.x), fabsf(a.y)), fmaxf(fabsf(a.z), fabsf(a.w))),
                  fmaxf(fmaxf(fabsf(b.x), fabsf(b.y)), fmaxf(fabsf(b.z), fabsf(b.w))));
  rmx[tid] = m;
  __syncthreads();
  for (int s = 128; s > 0; s >>= 1) {
    if (tid < s) rmx[tid] = fmaxf(rmx[tid], rmx[tid + s]);
    __syncthreads();
  }
  if (tid == 0) {
    float rm = rmx[0];
    sinv_s = rm > 0.f ? 32767.f / rm : 0.f;
    scale[row] = rm > 0.f ? rm / 32767.f : 0.f;
  }
  __syncthreads();
  const float inv = sinv_s;
  float w[8] = {a.x, a.y, a.z, a.w, b.x, b.y, b.z, b.w};
  int qi[8];
  #pragma unroll
  for (int j = 0; j < 8; ++j) {
    int v = __float2int_rn(w[j] * inv);
    qi[j] = max(-32767, min(32767, v));
  }
  uint4 out;
  out.x = ((uint)qi[0] & 0xffffu) | ((uint)qi[1] << 16);
  out.y = ((uint)qi[2] & 0xffffu) | ((uint)qi[3] << 16);
  out.z = ((uint)qi[4] & 0xffffu) | ((uint)qi[5] << 16);
  out.w = ((uint)qi[6] & 0xffffu) | ((uint)qi[7] << 16);
  q[((size_t)row * 4 + p) * 64 + lane] = out;
}

template <bool QUANT>
__global__ __launch_bounds__(NTH, 1) void lstm_persist(
    const float* __restrict__ y,
    const float* __restrict__ Wih1, const float* __restrict__ Whh1,
    const float* __restrict__ bih1, const float* __restrict__ bhh1,
    const float* __restrict__ Wih2, const float* __restrict__ Whh2,
    const float* __restrict__ bih2, const float* __restrict__ bhh2,
    const float* __restrict__ Wlin, const float* __restrict__ blin,
    float* __restrict__ out,
    const uint4* __restrict__ Q1, const float* __restrict__ S1,
    const uint4* __restrict__ Q2a, const float* __restrict__ S2a,
    const uint4* __restrict__ Q2b, const float* __restrict__ S2b,
    float* h1buf, float* h2buf, unsigned* flags1, unsigned* flags2)
{
  __shared__ __align__(16) float ldsH1[HH];
  __shared__ __align__(16) float ldsH2[HH];
  __shared__ float ldsX[DD];
  __shared__ float g1s[4][8];
  __shared__ float g2s[4][8];
  __shared__ float c1s[8];
  __shared__ float c2s[8];
  __shared__ float red[8];
  __shared__ float bsum1[32], bsum2[32];
  __shared__ float s1r[32], sAr[32], sBr[32];

  const int tid = threadIdx.x;
  const int wg = blockIdx.x;
  const int wave = tid >> 6;        // 0..7
  const int lane = tid & 63;
  const int gate = wave >> 1;       // 0..3 (i,f,g,o)
  const int half = wave & 1;        // which 4 of the WG's 8 rows
  const int rowbase = wg * 8;

  // ---- init ----
  for (int i = tid; i < HH; i += NTH) { ldsH1[i] = 0.0f; ldsH2[i] = 0.0f; }
  if (tid < 32) {
    int g = tid >> 3, sr2 = tid & 7;
    int grow = g * HH + rowbase + sr2;
    bsum1[tid] = bih1[grow] + bhh1[grow];
    bsum2[tid] = bih2[grow] + bhh2[grow];
    if constexpr (QUANT) {
      s1r[tid] = S1[grow];
      sAr[tid] = S2a[grow];
      sBr[tid] = S2b[grow];
    }
  }
  if (tid < 8) {
    c1s[tid] = 0.0f; c2s[tid] = 0.0f;
    __hip_atomic_store(&h2buf[HH + rowbase + tid], 0.0f, __ATOMIC_RELAXED, __HIP_MEMORY_SCOPE_AGENT);
  }
  __syncthreads();

  for (int t = 0; t < TT; ++t) {
    //================ phase 1: layer-1 gates (h1(t-1) in ldsH1) ================
    if (tid < DD) ldsX[tid] = y[t * DD + tid];
    __syncthreads();

    {
      float4 hf[8];
      const float4* H4 = (const float4*)ldsH1;
      #pragma unroll
      for (int m = 0; m < 8; ++m) hf[m] = H4[m * 64 + lane];

      #pragma unroll
      for (int r = 0; r < 4; ++r) {
        const int srow = half * 4 + r;
        const int grow = gate * HH + rowbase + srow;
        float v;
        if constexpr (QUANT) {
          const uint4* Qp = Q1 + ((size_t)grow * 4) * 64 + lane;
          float acc = 0.f;
          #pragma unroll
          for (int p = 0; p < 4; ++p)
            acc = dqdot(Qp[p * 64], hf[2 * p], hf[2 * p + 1], acc);
          v = acc * s1r[gate * 8 + srow];
        } else {
          const float4* Wr = (const float4*)(Whh1 + (size_t)grow * HH) + lane;
          float acc = 0.f;
          #pragma unroll
          for (int m = 0; m < 8; ++m) {
            const float4 wv = Wr[m * 64];
            acc = fmaf(wv.x, hf[m].x, acc); acc = fmaf(wv.y, hf[m].y, acc);
            acc = fmaf(wv.z, hf[m].z, acc); acc = fmaf(wv.w, hf[m].w, acc);
          }
          v = acc;
        }
        const float* Xr = Wih1 + (size_t)grow * DD;
        v += Xr[lane] * ldsX[lane];
        if (lane < DD - 64) v += Xr[64 + lane] * ldsX[64 + lane];
        v = wred(v);
        if (lane == 0) g1s[gate][srow] = v + bsum1[gate * 8 + srow];
      }
    }
    __syncthreads();

    if (tid < 8) {
      float gi = sigmoidf_(g1s[0][tid]);
      float gf = sigmoidf_(g1s[1][tid]);
      float gg = tanhf(g1s[2][tid]);
      float go = sigmoidf_(g1s[3][tid]);
      float c = fmaf(gf, c1s[tid], gi * gg);
      c1s[tid] = c;
      float h = go * tanhf(c);
      __hip_atomic_store(&h1buf[(t & 1) * HH + rowbase + tid], h,
                         __ATOMIC_RELAXED, __HIP_MEMORY_SCOPE_AGENT);
    }
    __syncthreads();
    if (tid == 0)
      __hip_atomic_store(&flags1[wg * FSTRIDE], (unsigned)(t + 1),
                         __ATOMIC_RELEASE, __HIP_MEMORY_SCOPE_AGENT);
    gbar_wait(flags1, (unsigned)(t + 1), tid);

    //================ phase 2: layer-2 gates; publish h2; out_{t-1} ================
    for (int i = tid; i < HH; i += NTH) {
      ldsH1[i] = __hip_atomic_load(&h1buf[(t & 1) * HH + i],
                                   __ATOMIC_RELAXED, __HIP_MEMORY_SCOPE_AGENT);
      ldsH2[i] = __hip_atomic_load(&h2buf[((t + 1) & 1) * HH + i],
                                   __ATOMIC_RELAXED, __HIP_MEMORY_SCOPE_AGENT);
    }
    __syncthreads();

    {
      float4 hf1[8], hf2[8];
      const float4* Ha = (const float4*)ldsH1;
      const float4* Hb = (const float4*)ldsH2;
      #pragma unroll
      for (int m = 0; m < 8; ++m) { hf1[m] = Ha[m * 64 + lane]; hf2[m] = Hb[m * 64 + lane]; }

      #pragma unroll
      for (int r = 0; r < 4; ++r) {
        const int srow = half * 4 + r;
        const int grow = gate * HH + rowbase + srow;
        float v;
        if constexpr (QUANT) {
          const uint4* Qa = Q2a + ((size_t)grow * 4) * 64 + lane;
          const uint4* Qb = Q2b + ((size_t)grow * 4) * 64 + lane;
          float aa = 0.f, ab = 0.f;
          #pragma unroll
          for (int p = 0; p < 4; ++p) {
            aa = dqdot(Qa[p * 64], hf1[2 * p], hf1[2 * p + 1], aa);
            ab = dqdot(Qb[p * 64], hf2[2 * p], hf2[2 * p + 1], ab);
          }
          v = aa * sAr[gate * 8 + srow] + ab * sBr[gate * 8 + srow];
        } else {
          const float4* Wa = (const float4*)(Wih2 + (size_t)grow * HH) + lane;
          const float4* Wb = (const float4*)(Whh2 + (size_t)grow * HH) + lane;
          float acc = 0.f;
          #pragma unroll
          for (int m = 0; m < 8; ++m) {
            const float4 a2 = Wa[m * 64], b2 = Wb[m * 64];
            acc = fmaf(a2.x, hf1[m].x, acc); acc = fmaf(a2.y, hf1[m].y, acc);
            acc = fmaf(a2.z, hf1[m].z, acc); acc = fmaf(a2.w, hf1[m].w, acc);
            acc = fmaf(b2.x, hf2[m].x, acc); acc = fmaf(b2.y, hf2[m].y, acc);
            acc = fmaf(b2.z, hf2[m].z, acc); acc = fmaf(b2.w, hf2[m].w, acc);
          }
          v = acc;
        }
        v = wred(v);
        if (lane == 0) g2s[gate][srow] = v + bsum2[gate * 8 + srow];
      }
    }
    __syncthreads();

    if (tid < 8) {
      float gi = sigmoidf_(g2s[0][tid]);
      float gf = sigmoidf_(g2s[1][tid]);
      float gg = tanhf(g2s[2][tid]);
      float go = sigmoidf_(g2s[3][tid]);
      float c = fmaf(gf, c2s[tid], gi * gg);
      c2s[tid] = c;
      float h = go * tanhf(c);
      __hip_atomic_store(&h2buf[(t & 1) * HH + rowbase + tid], h,
                         __ATOMIC_RELAXED, __HIP_MEMORY_SCOPE_AGENT);
    }
    __syncthreads();
    if (tid == 0)
      __hip_atomic_store(&flags2[wg * FSTRIDE], (unsigned)(t + 1),
                         __ATOMIC_RELEASE, __HIP_MEMORY_SCOPE_AGENT);

    // out_{t-1} = Wlin . h2(t-1) + blin; h2(t-1) already in ldsH2. Overlaps barrier wait.
    if (wg < DD && t >= PRE + 1) {
      const float4* Wr = (const float4*)(Wlin + (size_t)wg * HH);
      const float4* h4 = (const float4*)ldsH2;
      float4 wv = Wr[tid]; float4 hv = h4[tid];
      float p = wv.x * hv.x + wv.y * hv.y + wv.z * hv.z + wv.w * hv.w;
      p = wred(p);
      if (lane == 0) red[wave] = p;
      __syncthreads();
      if (tid == 0) {
        float o = blin[wg];
        #pragma unroll
        for (int w = 0; w < 8; ++w) o += red[w];
        out[(size_t)(t - 1 - PRE) * DD + wg] = o;
      }
    }

    gbar_wait(flags2, (unsigned)(t + 1), tid);
  }

  //================ epilogue: out for t = TT-1 ================
  if (wg < DD) {
    for (int i = tid; i < HH; i += NTH)
      ldsH2[i] = __hip_atomic_load(&h2buf[((TT - 1) & 1) * HH + i],
                                   __ATOMIC_RELAXED, __HIP_MEMORY_SCOPE_AGENT);
    __syncthreads();
    const float4* Wr = (const float4*)(Wlin + (size_t)wg * HH);
    const float4* h4 = (const float4*)ldsH2;
    float4 wv = Wr[tid]; float4 hv = h4[tid];
    float p = wv.x * hv.x + wv.y * hv.y + wv.z * hv.z + wv.w * hv.w;
    p = wred(p);
    if (lane == 0) red[wave] = p;
    __syncthreads();
    if (tid == 0) {
      float o = blin[wg];
      #pragma unroll
      for (int w = 0; w < 8; ++w) o += red[w];
      out[(size_t)(TT - 1 - PRE) * DD + wg] = o;
    }
  }
}

extern "C" void kernel_launch(void* const* d_in, const int* in_sizes, int n_in,
                              void* d_out, int out_size, void* d_ws, size_t ws_size,
                              hipStream_t stream) {
  const float* y    = (const float*)d_in[0];
  const float* Wih1 = (const float*)d_in[1];
  const float* Whh1 = (const float*)d_in[2];
  const float* bih1 = (const float*)d_in[3];
  const float* bhh1 = (const float*)d_in[4];
  const float* Wih2 = (const float*)d_in[5];
  const float* Whh2 = (const float*)d_in[6];
  const float* bih2 = (const float*)d_in[7];
  const float* bhh2 = (const float*)d_in[8];
  const float* Wlin = (const float*)d_in[9];
  const float* blin = (const float*)d_in[10];
  float* out = (float*)d_out;

  char* ws = (char*)d_ws;
  const size_t qB = (size_t)4 * HH * HH * 2;    // 33,554,432 per quantized matrix
  const size_t sB = (size_t)4 * HH * 4;         // 32,768 per scale array
  const size_t per = qB + sB;
  const size_t tail_bytes = (size_t)4 * HH * sizeof(float) + (size_t)2 * NWG * FSTRIDE * 4;
  const bool quant = ws_size >= 3 * per + tail_bytes;

  const uint4 *Q1 = nullptr, *Q2a = nullptr, *Q2b = nullptr;
  const float *S1 = nullptr, *S2a = nullptr, *S2b = nullptr;
  char* tail = ws;
  if (quant) {
    uint4* q1 = (uint4*)ws;              float* s1 = (float*)(ws + qB);
    uint4* q2 = (uint4*)(ws + per);      float* s2 = (float*)(ws + per + qB);
    uint4* q3 = (uint4*)(ws + 2 * per);  float* s3 = (float*)(ws + 2 * per + qB);
    tail = ws + 3 * per;
    pack_q16<<<4 * HH, 256, 0, stream>>>(Whh1, q1, s1);
    pack_q16<<<4 * HH, 256, 0, stream>>>(Wih2, q2, s2);
    pack_q16<<<4 * HH, 256, 0, stream>>>(Whh2, q3, s3);
    Q1 = q1; S1 = s1; Q2a = q2; S2a = s2; Q2b = q3; S2b = s3;
  }
  float* h1buf = (float*)tail;
  float* h2buf = h1buf + 2 * HH;
  unsigned* flags1 = (unsigned*)(h2buf + 2 * HH);
  unsigned* flags2 = flags1 + NWG * FSTRIDE;

  void* args[] = { &y, &Wih1, &Whh1, &bih1, &bhh1, &Wih2, &Whh2, &bih2, &bhh2,
                   &Wlin, &blin, &out,
                   &Q1, &S1, &Q2a, &S2a, &Q2b, &S2b,
                   &h1buf, &h2buf, &flags1, &flags2 };
  if (quant) {
    hipLaunchCooperativeKernel(reinterpret_cast<const void*>(lstm_persist<true>),
                               dim3(NWG), dim3(NTH), args, 0, stream);
  } else {
    hipLaunchCooperativeKernel(reinterpret_cast<const void*>(lstm_persist<false>),
                               dim3(NWG), dim3(NTH), args, 0, stream);
  }
}